// Round 10
// baseline (146.043 us; speedup 1.0000x reference)
//
#include <hip/hip_runtime.h>

// GIN: 2x GINConv(eps=0), N=50000, E=800000, d=128. bf16 + MFMA.
// R10: weight B-fragments hoisted to REGISTERS (tile-invariant per lane,
// 8x bf16x8 = 32 VGPR) + persistent blocks (grid 782, each does both 32-node
// halves of its bucket). Removes ~100MB/conv of L2 weight re-reads + L1
// thrash. Tests the request-cap theory; gather structure unchanged from R9.
// ws: [ xb 12.8M | zb 12.8M | wt 128K | gcnt 4K | ebuf 4.8M | sbuf 2.4M | noff 204K ]

#define NN 50000
#define NE 800000
#define FD 128
#define BNODES 64
#define NB 782           // buckets; also conv grid (2 tiles per block)
#define BCAP 1536        // max edges/bucket: mean 1024, sigma 32 -> +16 sigma
#define EPW 4096
#define NWG_BIN 196      // ceil(NE/EPW)

typedef unsigned short u16;
typedef unsigned int u32;
typedef __attribute__((ext_vector_type(8))) short bf16x8;
typedef __attribute__((ext_vector_type(4))) float f32x4;

static __device__ __forceinline__ float b2f(u16 u) {
    return __uint_as_float(((u32)u) << 16);
}
static __device__ __forceinline__ u16 f2b(float f) {
    u32 x = __float_as_uint(f);
    u32 r = x + 0x7FFFu + ((x >> 16) & 1u);   // RNE
    return (u16)(r >> 16);
}

// unpack-accumulate a uint4 (8 bf16) into acc0/acc1 via exact float-bit tricks
#define ACCUM(v) do { \
    acc0.x += __uint_as_float((v).x << 16); \
    acc0.y += __uint_as_float((v).x & 0xFFFF0000u); \
    acc0.z += __uint_as_float((v).y << 16); \
    acc0.w += __uint_as_float((v).y & 0xFFFF0000u); \
    acc1.x += __uint_as_float((v).z << 16); \
    acc1.y += __uint_as_float((v).z & 0xFFFF0000u); \
    acc1.z += __uint_as_float((v).w << 16); \
    acc1.w += __uint_as_float((v).w & 0xFFFF0000u); } while (0)

// ---------------- converts ----------------

__global__ __launch_bounds__(256) void convert_x_kernel(
    const float* __restrict__ x, u16* __restrict__ xb)
{
    int gid = blockIdx.x * 256 + threadIdx.x;
    size_t base = (size_t)gid * 8;
    float4 a = *reinterpret_cast<const float4*>(x + base);
    float4 b = *reinterpret_cast<const float4*>(x + base + 4);
    u32 w0 = (u32)f2b(a.x) | ((u32)f2b(a.y) << 16);
    u32 w1 = (u32)f2b(a.z) | ((u32)f2b(a.w) << 16);
    u32 w2 = (u32)f2b(b.x) | ((u32)f2b(b.y) << 16);
    u32 w3 = (u32)f2b(b.z) | ((u32)f2b(b.w) << 16);
    uint4 o = {w0, w1, w2, w3};
    *reinterpret_cast<uint4*>(xb + base) = o;
}

// W [128][128] fp32 row-major -> WT[n][k] = W[k][n] bf16
__global__ __launch_bounds__(256) void convert_w_kernel(
    const float* __restrict__ w0, const float* __restrict__ w1,
    const float* __restrict__ w2, const float* __restrict__ w3,
    u16* __restrict__ wt)
{
    int b = blockIdx.x;
    const float* W = (b == 0) ? w0 : (b == 1) ? w1 : (b == 2) ? w2 : w3;
    u16* out = wt + (size_t)b * FD * FD;
    for (int idx = threadIdx.x; idx < FD * FD; idx += 256) {
        int n = idx >> 7, k = idx & 127;
        out[idx] = f2b(W[k * FD + n]);
    }
}

// ---------------- bucket binning (64-node buckets) ----------------

__global__ __launch_bounds__(256) void bin_kernel(
    const int* __restrict__ ei, u32* __restrict__ ebuf, int* __restrict__ gcnt)
{
    __shared__ int cnt[1024];
    __shared__ int lofs[1024];
    __shared__ int cur[1024];
    __shared__ int gb[1024];
    __shared__ int csum[16];
    __shared__ int cofs[16];
    __shared__ u32 vals[EPW];
    __shared__ u16 bkt[EPW];

    const int tid = threadIdx.x, lane = tid & 63, wv = tid >> 6;
    const int e0 = blockIdx.x * EPW;
    const int nE = min(EPW, NE - e0);
    const int* dstp = ei + NE;

    for (int i = tid; i < 1024; i += 256) { cnt[i] = 0; cur[i] = 0; }
    __syncthreads();

    for (int k = 0; k < EPW / 256; ++k) {
        int e = e0 + k * 256 + tid;
        if (e < NE) atomicAdd(&cnt[(u32)dstp[e] >> 6], 1);
    }
    __syncthreads();

    // exclusive scan over 1024 slots (16 chunks of 64)
    for (int cc = 0; cc < 4; ++cc) {
        int c = wv + cc * 4;
        int i = c * 64 + lane;
        int v = cnt[i];
        int sc = v;
#pragma unroll
        for (int s = 1; s < 64; s <<= 1) {
            int t = __shfl_up(sc, s);
            if (lane >= s) sc += t;
        }
        lofs[i] = sc - v;
        if (lane == 63) csum[c] = sc;
    }
    __syncthreads();
    if (wv == 0) {
        int s = (lane < 16) ? csum[lane] : 0;
        int sc = s;
#pragma unroll
        for (int st = 1; st < 16; st <<= 1) {
            int u = __shfl_up(sc, st);
            if (lane >= st) sc += u;
        }
        if (lane < 16) cofs[lane] = sc - s;
    }
    __syncthreads();
    for (int cc = 0; cc < 4; ++cc) {
        int c = wv + cc * 4;
        lofs[c * 64 + lane] += cofs[c];
    }
    __syncthreads();

    // place (bucket-grouped in LDS)
    for (int k = 0; k < EPW / 256; ++k) {
        int e = e0 + k * 256 + tid;
        if (e < NE) {
            int s = ei[e];
            u32 d = (u32)dstp[e];
            int b = d >> 6;
            int p = lofs[b] + atomicAdd(&cur[b], 1);
            vals[p] = (u32)s | ((d & 63u) << 16);
            bkt[p] = (u16)b;
        }
    }
    __syncthreads();

    // claim global chunks
    for (int b = tid; b < NB; b += 256) {
        int c = cur[b];
        gb[b] = c ? atomicAdd(&gcnt[b], c) : 0;
    }
    __syncthreads();

    // flush bucket-grouped -> contiguous runs
    for (int idx = tid; idx < nE; idx += 256) {
        int b = bkt[idx];
        ebuf[(size_t)b * BCAP + gb[b] + (idx - lofs[b])] = vals[idx];
    }
}

// ---------------- one-time counting sort per bucket ----------------

__global__ __launch_bounds__(256) void sort_kernel(
    const u32* __restrict__ ebuf, const int* __restrict__ gcnt,
    u16* __restrict__ sbuf, int* __restrict__ noff)
{
    __shared__ u32 stage[BCAP];    // 6 KB
    __shared__ u16 sorted[BCAP];   // 3 KB
    __shared__ int cnt64[64];
    __shared__ int off64[65];
    __shared__ int cur64[64];

    const int tid = threadIdx.x, lane = tid & 63, wv = tid >> 6;
    const int b = blockIdx.x;
    const int cnt = gcnt[b];
    const u32* eb = ebuf + (size_t)b * BCAP;

    if (tid < 64) cnt64[tid] = 0;
    __syncthreads();

    for (int e = tid; e < cnt; e += 256) {
        u32 v = eb[e];
        stage[e] = v;
        atomicAdd(&cnt64[v >> 16], 1);
    }
    __syncthreads();

    if (wv == 0) {
        int v = cnt64[lane];
        int sc = v;
#pragma unroll
        for (int s = 1; s < 64; s <<= 1) {
            int t = __shfl_up(sc, s);
            if (lane >= s) sc += t;
        }
        off64[lane + 1] = sc;
        cur64[lane] = sc - v;
        if (lane == 0) off64[0] = 0;
    }
    __syncthreads();

    for (int e = tid; e < cnt; e += 256) {
        u32 v = stage[e];
        int pos = atomicAdd(&cur64[v >> 16], 1);
        sorted[pos] = (u16)(v & 0xFFFFu);   // src < 50000 fits u16
    }
    __syncthreads();

    if (tid < 65) noff[b * 65 + tid] = off64[tid];
    u32* sb = (u32*)(sbuf + (size_t)b * BCAP);
    const u32* so = (const u32*)sorted;
    for (int i = tid; i * 2 < cnt; i += 256) sb[i] = so[i];
}

// ---------------- fused conv: persistent block, 2x 32-node tiles ----------
// Block = bucket; iterates its two 32-node halves. Weight B-frags + biases
// loaded ONCE into registers (tile-invariant: col = wv*16+l16). Gather
// unchanged from R9: 16-lane group per node, dwordx4 reads, 4-deep batches.
// k-map phi(g,i)=8g+i both operands; D: col=lane&15, row=(lane>>4)*4+reg.

template <bool F32OUT>
__global__ __launch_bounds__(512, 8) void conv_kernel(
    const u16* __restrict__ h, const u16* __restrict__ sbuf,
    const int* __restrict__ noff,
    const u16* __restrict__ WTa, const float* __restrict__ biasa,
    const u16* __restrict__ WTb, const float* __restrict__ biasb,
    void* __restrict__ outv)
{
    __shared__ u16 a_lds[32][136];   // 8.7 KB
    __shared__ u16 t_lds[32][136];   // 8.7 KB
    __shared__ u16 sorted[1024];     // 2 KB
    __shared__ int off[33];

    const int tid = threadIdx.x;
    const int lane = tid & 63;
    const int wv = tid >> 6;          // 0..7
    const int b = blockIdx.x;         // bucket
    const int g = lane >> 4;          // group-in-wave 0..3
    const int l16 = lane & 15;
    const int gid = wv * 4 + g;       // 0..31: this group's node within tile
    const int col = wv * 16 + l16;    // this lane's output column (both GEMMs)

    // ---- one-time: weight fragments + biases into registers ----
    bf16x8 wa[4], wb[4];
#pragma unroll
    for (int k0 = 0; k0 < 4; ++k0) {
        const int kk = k0 * 32 + g * 8;
        wa[k0] = *reinterpret_cast<const bf16x8*>(WTa + (size_t)col * FD + kk);
        wb[k0] = *reinterpret_cast<const bf16x8*>(WTb + (size_t)col * FD + kk);
    }
    const float bca = biasa[col];
    const float bcb = biasb[col];
    const u16* hcol = h + l16 * 8;    // this lane's 8-feature slice

    for (int hh = 0; hh < 2; ++hh) {
        const int node0 = b * BNODES + hh * 32;
        const int nNodes = min(32, NN - node0);

        // ---- phase 1: offsets + sorted slice ----
        if (tid < 33) off[tid] = noff[b * 65 + hh * 32 + tid];
        __syncthreads();
        const int base0 = off[0];
        const int ecnt = off[32] - base0;
        {
            const u16* sb = sbuf + (size_t)b * BCAP + base0;
            for (int i = tid; i < ecnt; i += 512) sorted[i] = sb[i];
        }
        __syncthreads();

        // ---- phase 2: gather into a_lds ----
        float4 acc0 = {0.f, 0.f, 0.f, 0.f};
        float4 acc1 = {0.f, 0.f, 0.f, 0.f};
        if (gid < nNodes) {
            uint4 v = *reinterpret_cast<const uint4*>(hcol + (size_t)(node0 + gid) * FD);
            ACCUM(v);   // self term
            const int beg = off[gid] - base0;
            const int end = off[gid + 1] - base0;
            for (int e = beg; e < end; e += 4) {
                const int m = end - e;
                uint4 vv[4];
#pragma unroll
                for (int k = 0; k < 4; ++k) {
                    int ee = e + k; if (ee > end - 1) ee = end - 1;  // dup tail: L1-hit
                    int s = sorted[ee];
                    vv[k] = *reinterpret_cast<const uint4*>(hcol + (size_t)s * FD);
                }
                ACCUM(vv[0]);
                if (m > 1) ACCUM(vv[1]);
                if (m > 2) ACCUM(vv[2]);
                if (m > 3) ACCUM(vv[3]);
            }
        }
        {
            uint4 o;
            o.x = (u32)f2b(acc0.x) | ((u32)f2b(acc0.y) << 16);
            o.y = (u32)f2b(acc0.z) | ((u32)f2b(acc0.w) << 16);
            o.z = (u32)f2b(acc1.x) | ((u32)f2b(acc1.y) << 16);
            o.w = (u32)f2b(acc1.z) | ((u32)f2b(acc1.w) << 16);
            *reinterpret_cast<uint4*>(&a_lds[gid][l16 * 8]) = o;   // zeros for pad rows
        }
        __syncthreads();

        // ---- phase 3: t = relu(a @ Wa + ba) ----
        f32x4 acc[2];
        acc[0] = (f32x4){0.f, 0.f, 0.f, 0.f};
        acc[1] = (f32x4){0.f, 0.f, 0.f, 0.f};
#pragma unroll
        for (int k0 = 0; k0 < 4; ++k0) {
            const int kk = k0 * 32 + g * 8;
            bf16x8 a0 = *reinterpret_cast<const bf16x8*>(&a_lds[l16][kk]);
            bf16x8 a1 = *reinterpret_cast<const bf16x8*>(&a_lds[16 + l16][kk]);
            acc[0] = __builtin_amdgcn_mfma_f32_16x16x32_bf16(a0, wa[k0], acc[0], 0, 0, 0);
            acc[1] = __builtin_amdgcn_mfma_f32_16x16x32_bf16(a1, wa[k0], acc[1], 0, 0, 0);
        }
#pragma unroll
        for (int m = 0; m < 2; ++m)
#pragma unroll
            for (int r = 0; r < 4; ++r) {
                int row = 16 * m + g * 4 + r;
                t_lds[row][col] = f2b(fmaxf(acc[m][r] + bca, 0.f));
            }
        __syncthreads();

        // ---- phase 4: out = relu(t @ Wb + bb) ----
        f32x4 acc2[2];
        acc2[0] = (f32x4){0.f, 0.f, 0.f, 0.f};
        acc2[1] = (f32x4){0.f, 0.f, 0.f, 0.f};
#pragma unroll
        for (int k0 = 0; k0 < 4; ++k0) {
            const int kk = k0 * 32 + g * 8;
            bf16x8 a0 = *reinterpret_cast<const bf16x8*>(&t_lds[l16][kk]);
            bf16x8 a1 = *reinterpret_cast<const bf16x8*>(&t_lds[16 + l16][kk]);
            acc2[0] = __builtin_amdgcn_mfma_f32_16x16x32_bf16(a0, wb[k0], acc2[0], 0, 0, 0);
            acc2[1] = __builtin_amdgcn_mfma_f32_16x16x32_bf16(a1, wb[k0], acc2[1], 0, 0, 0);
        }

        if (F32OUT) {
#pragma unroll
            for (int m = 0; m < 2; ++m)
#pragma unroll
                for (int r = 0; r < 4; ++r) {
                    int row = node0 + 16 * m + g * 4 + r;
                    if (row < NN) {
                        float v = fmaxf(acc2[m][r] + bcb, 0.f);
                        reinterpret_cast<float*>(outv)[(size_t)row * FD + col] = v;
                    }
                }
        } else {
            // stage bf16 in a_lds (free after phase 4 reads), coalesced copy-out
#pragma unroll
            for (int m = 0; m < 2; ++m)
#pragma unroll
                for (int r = 0; r < 4; ++r) {
                    int row = 16 * m + g * 4 + r;
                    a_lds[row][col] = f2b(fmaxf(acc2[m][r] + bcb, 0.f));
                }
            __syncthreads();
            u16* outp = reinterpret_cast<u16*>(outv);
            int r = tid >> 4, c = (tid & 15) * 8;
            if (node0 + r < NN)
                *reinterpret_cast<uint4*>(outp + (size_t)(node0 + r) * FD + c) =
                    *reinterpret_cast<const uint4*>(&a_lds[r][c]);
        }
        __syncthreads();   // protect off/sorted/a_lds before next tile
    }
}

extern "C" void kernel_launch(void* const* d_in, const int* in_sizes, int n_in,
                              void* d_out, int out_size, void* d_ws, size_t ws_size,
                              hipStream_t stream) {
    const float* x   = (const float*)d_in[0];
    const int*   ei  = (const int*)d_in[1];
    const float* W1a = (const float*)d_in[2];
    const float* b1a = (const float*)d_in[3];
    const float* W1b = (const float*)d_in[4];
    const float* b1b = (const float*)d_in[5];
    const float* W2a = (const float*)d_in[6];
    const float* b2a = (const float*)d_in[7];
    const float* W2b = (const float*)d_in[8];
    const float* b2b = (const float*)d_in[9];

    const size_t feat = (size_t)NN * FD;
    u16* xb = (u16*)d_ws;             // 12.8 MB (x bf16)
    u16* zb = xb + feat;              // 12.8 MB (h1 bf16)
    u16* wt = zb + feat;              // 128 KB
    int* gcnt = (int*)(wt + 4 * FD * FD);       // 1024 ints
    u32* ebuf = (u32*)(gcnt + 1024);            // NB*BCAP*4 = 4.80 MB
    u16* sbuf = (u16*)(ebuf + (size_t)NB * BCAP); // NB*BCAP*2 = 2.40 MB
    int* noff = (int*)(sbuf + (size_t)NB * BCAP); // NB*65*4 = 204 KB

    const int cBlocks = (int)(feat / (256 * 8));// 3125

    convert_x_kernel<<<cBlocks, 256, 0, stream>>>(x, xb);
    convert_w_kernel<<<4, 256, 0, stream>>>(W1a, W1b, W2a, W2b, wt);

    hipMemsetAsync(gcnt, 0, NB * sizeof(int), stream);
    bin_kernel<<<NWG_BIN, 256, 0, stream>>>(ei, ebuf, gcnt);
    sort_kernel<<<NB, 256, 0, stream>>>(ebuf, gcnt, sbuf, noff);

    // conv1: xb -> zb (bf16)
    conv_kernel<false><<<NB, 512, 0, stream>>>(
        xb, sbuf, noff, wt, b1a, wt + 1 * FD * FD, b1b, zb);
    // conv2: zb -> d_out (fp32)
    conv_kernel<true><<<NB, 512, 0, stream>>>(
        zb, sbuf, noff, wt + 2 * FD * FD, b2a, wt + 3 * FD * FD, b2b, (float*)d_out);
}

// Round 11
// 134.067 us; speedup vs baseline: 1.0893x; 1.0893x over previous
//
#include <hip/hip_runtime.h>

// GIN: 2x GINConv(eps=0), N=50000, E=800000, d=128. bf16 + MFMA.
// R11: R8 structure (64-node tile, grid 782, best so far) + software-pipelined
// gather: two 4-deep uint4 batches (va/vb), batch k+1 issued BEFORE batch k is
// accumulated -> ACCUM hides under load latency, 8 loads outstanding (was 4,
// fully serialized: VALUBusy 20% = accum duty cycle). R9 (more waves) and R10
// (fewer requests) both nulled -> latency-overlap is the remaining lever.
// ws: [ xb 12.8M | zb 12.8M | wt 128K | gcnt 4K | ebuf 4.8M | sbuf 2.4M | noff 204K ]

#define NN 50000
#define NE 800000
#define FD 128
#define BNODES 64
#define NB 782           // ceil(NN/64); bucket 781 has 16 nodes
#define BCAP 1536        // max edges/bucket: mean 1024, sigma 32 -> +16 sigma
#define EPW 4096
#define NWG_BIN 196      // ceil(NE/EPW)

typedef unsigned short u16;
typedef unsigned int u32;
typedef __attribute__((ext_vector_type(8))) short bf16x8;
typedef __attribute__((ext_vector_type(4))) float f32x4;

static __device__ __forceinline__ float b2f(u16 u) {
    return __uint_as_float(((u32)u) << 16);
}
static __device__ __forceinline__ u16 f2b(float f) {
    u32 x = __float_as_uint(f);
    u32 r = x + 0x7FFFu + ((x >> 16) & 1u);   // RNE
    return (u16)(r >> 16);
}

// unpack-accumulate a uint4 (8 bf16) into acc0/acc1 via exact float-bit tricks
#define ACCUM(v) do { \
    acc0.x += __uint_as_float((v).x << 16); \
    acc0.y += __uint_as_float((v).x & 0xFFFF0000u); \
    acc0.z += __uint_as_float((v).y << 16); \
    acc0.w += __uint_as_float((v).y & 0xFFFF0000u); \
    acc1.x += __uint_as_float((v).z << 16); \
    acc1.y += __uint_as_float((v).z & 0xFFFF0000u); \
    acc1.z += __uint_as_float((v).w << 16); \
    acc1.w += __uint_as_float((v).w & 0xFFFF0000u); } while (0)

// clamped 4-deep batch load (dup tail rows: L1-hit, masked at accumulate)
#define LOADB(vv, e0) do { \
    _Pragma("unroll") \
    for (int k = 0; k < 4; ++k) { \
        int ee = (e0) + k; if (ee > endm1) ee = endm1; \
        vv[k] = *reinterpret_cast<const uint4*>(hcol + (size_t)sorted[ee] * FD); \
    } } while (0)

#define ACCUMB(vv, m) do { \
    ACCUM(vv[0]); \
    if ((m) > 1) ACCUM(vv[1]); \
    if ((m) > 2) ACCUM(vv[2]); \
    if ((m) > 3) ACCUM(vv[3]); } while (0)

// ---------------- converts ----------------

__global__ __launch_bounds__(256) void convert_x_kernel(
    const float* __restrict__ x, u16* __restrict__ xb)
{
    int gid = blockIdx.x * 256 + threadIdx.x;
    size_t base = (size_t)gid * 8;
    float4 a = *reinterpret_cast<const float4*>(x + base);
    float4 b = *reinterpret_cast<const float4*>(x + base + 4);
    u32 w0 = (u32)f2b(a.x) | ((u32)f2b(a.y) << 16);
    u32 w1 = (u32)f2b(a.z) | ((u32)f2b(a.w) << 16);
    u32 w2 = (u32)f2b(b.x) | ((u32)f2b(b.y) << 16);
    u32 w3 = (u32)f2b(b.z) | ((u32)f2b(b.w) << 16);
    uint4 o = {w0, w1, w2, w3};
    *reinterpret_cast<uint4*>(xb + base) = o;
}

// W [128][128] fp32 row-major -> WT[n][k] = W[k][n] bf16
__global__ __launch_bounds__(256) void convert_w_kernel(
    const float* __restrict__ w0, const float* __restrict__ w1,
    const float* __restrict__ w2, const float* __restrict__ w3,
    u16* __restrict__ wt)
{
    int b = blockIdx.x;
    const float* W = (b == 0) ? w0 : (b == 1) ? w1 : (b == 2) ? w2 : w3;
    u16* out = wt + (size_t)b * FD * FD;
    for (int idx = threadIdx.x; idx < FD * FD; idx += 256) {
        int n = idx >> 7, k = idx & 127;
        out[idx] = f2b(W[k * FD + n]);
    }
}

// ---------------- bucket binning (64-node buckets) ----------------

__global__ __launch_bounds__(256) void bin_kernel(
    const int* __restrict__ ei, u32* __restrict__ ebuf, int* __restrict__ gcnt)
{
    __shared__ int cnt[1024];
    __shared__ int lofs[1024];
    __shared__ int cur[1024];
    __shared__ int gb[1024];
    __shared__ int csum[16];
    __shared__ int cofs[16];
    __shared__ u32 vals[EPW];
    __shared__ u16 bkt[EPW];

    const int tid = threadIdx.x, lane = tid & 63, wv = tid >> 6;
    const int e0 = blockIdx.x * EPW;
    const int nE = min(EPW, NE - e0);
    const int* dstp = ei + NE;

    for (int i = tid; i < 1024; i += 256) { cnt[i] = 0; cur[i] = 0; }
    __syncthreads();

    for (int k = 0; k < EPW / 256; ++k) {
        int e = e0 + k * 256 + tid;
        if (e < NE) atomicAdd(&cnt[(u32)dstp[e] >> 6], 1);
    }
    __syncthreads();

    // exclusive scan over 1024 slots (16 chunks of 64)
    for (int cc = 0; cc < 4; ++cc) {
        int c = wv + cc * 4;
        int i = c * 64 + lane;
        int v = cnt[i];
        int sc = v;
#pragma unroll
        for (int s = 1; s < 64; s <<= 1) {
            int t = __shfl_up(sc, s);
            if (lane >= s) sc += t;
        }
        lofs[i] = sc - v;
        if (lane == 63) csum[c] = sc;
    }
    __syncthreads();
    if (wv == 0) {
        int s = (lane < 16) ? csum[lane] : 0;
        int sc = s;
#pragma unroll
        for (int st = 1; st < 16; st <<= 1) {
            int u = __shfl_up(sc, st);
            if (lane >= st) sc += u;
        }
        if (lane < 16) cofs[lane] = sc - s;
    }
    __syncthreads();
    for (int cc = 0; cc < 4; ++cc) {
        int c = wv + cc * 4;
        lofs[c * 64 + lane] += cofs[c];
    }
    __syncthreads();

    // place (bucket-grouped in LDS)
    for (int k = 0; k < EPW / 256; ++k) {
        int e = e0 + k * 256 + tid;
        if (e < NE) {
            int s = ei[e];
            u32 d = (u32)dstp[e];
            int b = d >> 6;
            int p = lofs[b] + atomicAdd(&cur[b], 1);
            vals[p] = (u32)s | ((d & 63u) << 16);
            bkt[p] = (u16)b;
        }
    }
    __syncthreads();

    // claim global chunks
    for (int b = tid; b < NB; b += 256) {
        int c = cur[b];
        gb[b] = c ? atomicAdd(&gcnt[b], c) : 0;
    }
    __syncthreads();

    // flush bucket-grouped -> contiguous runs
    for (int idx = tid; idx < nE; idx += 256) {
        int b = bkt[idx];
        ebuf[(size_t)b * BCAP + gb[b] + (idx - lofs[b])] = vals[idx];
    }
}

// ---------------- one-time counting sort per bucket ----------------

__global__ __launch_bounds__(256) void sort_kernel(
    const u32* __restrict__ ebuf, const int* __restrict__ gcnt,
    u16* __restrict__ sbuf, int* __restrict__ noff)
{
    __shared__ u32 stage[BCAP];    // 6 KB
    __shared__ u16 sorted[BCAP];   // 3 KB
    __shared__ int cnt64[64];
    __shared__ int off64[65];
    __shared__ int cur64[64];

    const int tid = threadIdx.x, lane = tid & 63, wv = tid >> 6;
    const int b = blockIdx.x;
    const int cnt = gcnt[b];
    const u32* eb = ebuf + (size_t)b * BCAP;

    if (tid < 64) cnt64[tid] = 0;
    __syncthreads();

    for (int e = tid; e < cnt; e += 256) {
        u32 v = eb[e];
        stage[e] = v;
        atomicAdd(&cnt64[v >> 16], 1);
    }
    __syncthreads();

    if (wv == 0) {
        int v = cnt64[lane];
        int sc = v;
#pragma unroll
        for (int s = 1; s < 64; s <<= 1) {
            int t = __shfl_up(sc, s);
            if (lane >= s) sc += t;
        }
        off64[lane + 1] = sc;
        cur64[lane] = sc - v;
        if (lane == 0) off64[0] = 0;
    }
    __syncthreads();

    for (int e = tid; e < cnt; e += 256) {
        u32 v = stage[e];
        int pos = atomicAdd(&cur64[v >> 16], 1);
        sorted[pos] = (u16)(v & 0xFFFFu);   // src < 50000 fits u16
    }
    __syncthreads();

    if (tid < 65) noff[b * 65 + tid] = off64[tid];
    u32* sb = (u32*)(sbuf + (size_t)b * BCAP);
    const u32* so = (const u32*)sorted;
    for (int i = tid; i * 2 < cnt; i += 256) sb[i] = so[i];
}

// ---------------- fused conv (R8 structure + pipelined gather) ----------
// Block = bucket = M-tile (64 nodes). 8 waves. Gather: 16-lane group per node
// (q-loop of 2 nodes/group), dwordx4 reads, double-buffered 4-deep batches.
// GEMM: 8 waves as 2Mx4N; weights read as B-frags from global (L2-resident).
// k-map phi(g,i)=8g+i both operands; D: col=lane&15, row=(lane>>4)*4+reg.

template <bool F32OUT>
__global__ __launch_bounds__(512, 6) void conv_kernel(
    const u16* __restrict__ h, const u16* __restrict__ sbuf,
    const int* __restrict__ noff,
    const u16* __restrict__ WTa, const float* __restrict__ biasa,
    const u16* __restrict__ WTb, const float* __restrict__ biasb,
    void* __restrict__ outv)
{
    __shared__ u16 a_lds[64][136];   // 17.4 KB
    __shared__ u16 t_lds[64][136];   // 17.4 KB
    __shared__ u16 sorted[BCAP];     // 3 KB
    __shared__ int off[65];

    const int tid = threadIdx.x;
    const int lane = tid & 63;
    const int wv = tid >> 6;         // 0..7
    const int b = blockIdx.x;
    const int node0 = b * BNODES;
    const int nNodes = min(BNODES, NN - node0);
    const int g = lane >> 4;         // group 0..3
    const int l16 = lane & 15;

    // ---- phase 1: load sorted edge list + offsets ----
    if (tid < 65) off[tid] = noff[b * 65 + tid];
    __syncthreads();
    const int cnt = off[64];
    {
        const u32* sb = (const u32*)(sbuf + (size_t)b * BCAP);
        u32* so = (u32*)sorted;
        for (int i = tid; i * 2 < cnt; i += 512) so[i] = sb[i];
    }
    __syncthreads();

    // ---- phase 2: gather into a_lds (group g handles node q*4+g) ----
    const u16* hcol = h + l16 * 8;   // this lane's 8-feature slice

    for (int q = wv; q < 16; q += 8) {
        const int n = q * 4 + g;
        float4 acc0 = {0.f, 0.f, 0.f, 0.f};
        float4 acc1 = {0.f, 0.f, 0.f, 0.f};
        if (n < nNodes) {
            uint4 v = *reinterpret_cast<const uint4*>(hcol + (size_t)(node0 + n) * FD);
            ACCUM(v);   // self term
            const int end = off[n + 1];
            const int endm1 = end - 1;
            int e = off[n];
            if (e < end) {
                uint4 va[4], vb[4];
                LOADB(va, e);                       // prologue
                while (true) {
                    int e2 = e + 4;
                    if (e2 < end) LOADB(vb, e2);    // prefetch BEFORE accum
                    ACCUMB(va, end - e);
                    e = e2;
                    if (e >= end) break;
                    int e3 = e + 4;
                    if (e3 < end) LOADB(va, e3);
                    ACCUMB(vb, end - e);
                    e = e3;
                    if (e >= end) break;
                }
            }
        }
        uint4 o;
        o.x = (u32)f2b(acc0.x) | ((u32)f2b(acc0.y) << 16);
        o.y = (u32)f2b(acc0.z) | ((u32)f2b(acc0.w) << 16);
        o.z = (u32)f2b(acc1.x) | ((u32)f2b(acc1.y) << 16);
        o.w = (u32)f2b(acc1.z) | ((u32)f2b(acc1.w) << 16);
        *reinterpret_cast<uint4*>(&a_lds[n][l16 * 8]) = o;   // zeros for pad rows
    }
    __syncthreads();

    const int mbase = (wv >> 2) * 32;   // 0 or 32
    const int nbase = (wv & 3) * 32;    // 0,32,64,96

    // ---- phase 3: t = relu(a @ Wa + ba) ----
    f32x4 acc[2][2];
#pragma unroll
    for (int m = 0; m < 2; ++m)
#pragma unroll
        for (int nf = 0; nf < 2; ++nf) acc[m][nf] = (f32x4){0.f, 0.f, 0.f, 0.f};

#pragma unroll
    for (int k0 = 0; k0 < 4; ++k0) {
        const int kk = k0 * 32 + g * 8;
        bf16x8 a0 = *reinterpret_cast<const bf16x8*>(&a_lds[mbase + l16][kk]);
        bf16x8 a1 = *reinterpret_cast<const bf16x8*>(&a_lds[mbase + 16 + l16][kk]);
#pragma unroll
        for (int nf = 0; nf < 2; ++nf) {
            bf16x8 bb = *reinterpret_cast<const bf16x8*>(
                WTa + (size_t)(nbase + nf * 16 + l16) * FD + kk);
            acc[0][nf] = __builtin_amdgcn_mfma_f32_16x16x32_bf16(a0, bb, acc[0][nf], 0, 0, 0);
            acc[1][nf] = __builtin_amdgcn_mfma_f32_16x16x32_bf16(a1, bb, acc[1][nf], 0, 0, 0);
        }
    }

#pragma unroll
    for (int m = 0; m < 2; ++m) {
#pragma unroll
        for (int nf = 0; nf < 2; ++nf) {
            int col = nbase + nf * 16 + l16;
            float bc = biasa[col];
#pragma unroll
            for (int r = 0; r < 4; ++r) {
                int row = mbase + 16 * m + g * 4 + r;
                t_lds[row][col] = f2b(fmaxf(acc[m][nf][r] + bc, 0.f));
            }
        }
    }
    __syncthreads();

    // ---- phase 4: out = relu(t @ Wb + bb) ----
    f32x4 acc2[2][2];
#pragma unroll
    for (int m = 0; m < 2; ++m)
#pragma unroll
        for (int nf = 0; nf < 2; ++nf) acc2[m][nf] = (f32x4){0.f, 0.f, 0.f, 0.f};

#pragma unroll
    for (int k0 = 0; k0 < 4; ++k0) {
        const int kk = k0 * 32 + g * 8;
        bf16x8 a0 = *reinterpret_cast<const bf16x8*>(&t_lds[mbase + l16][kk]);
        bf16x8 a1 = *reinterpret_cast<const bf16x8*>(&t_lds[mbase + 16 + l16][kk]);
#pragma unroll
        for (int nf = 0; nf < 2; ++nf) {
            bf16x8 bb = *reinterpret_cast<const bf16x8*>(
                WTb + (size_t)(nbase + nf * 16 + l16) * FD + kk);
            acc2[0][nf] = __builtin_amdgcn_mfma_f32_16x16x32_bf16(a0, bb, acc2[0][nf], 0, 0, 0);
            acc2[1][nf] = __builtin_amdgcn_mfma_f32_16x16x32_bf16(a1, bb, acc2[1][nf], 0, 0, 0);
        }
    }

    if (F32OUT) {
        // f32 frag stores are already full-line (16 consecutive f32 = 64B)
#pragma unroll
        for (int m = 0; m < 2; ++m) {
#pragma unroll
            for (int nf = 0; nf < 2; ++nf) {
                int col = nbase + nf * 16 + l16;
                float bc = biasb[col];
#pragma unroll
                for (int r = 0; r < 4; ++r) {
                    int row = node0 + mbase + 16 * m + g * 4 + r;
                    if (row < NN) {
                        float v = fmaxf(acc2[m][nf][r] + bc, 0.f);
                        reinterpret_cast<float*>(outv)[(size_t)row * FD + col] = v;
                    }
                }
            }
        }
    } else {
        // stage bf16 result in t_lds (free after phase 4 reads), then
        // coalesced 16B/lane copy-out — avoids 2x partial-line writebacks.
        __syncthreads();
#pragma unroll
        for (int m = 0; m < 2; ++m) {
#pragma unroll
            for (int nf = 0; nf < 2; ++nf) {
                int col = nbase + nf * 16 + l16;
                float bc = biasb[col];
#pragma unroll
                for (int r = 0; r < 4; ++r) {
                    int row = mbase + 16 * m + g * 4 + r;
                    t_lds[row][col] = f2b(fmaxf(acc2[m][nf][r] + bc, 0.f));
                }
            }
        }
        __syncthreads();
        u16* outp = reinterpret_cast<u16*>(outv);
#pragma unroll
        for (int it = 0; it < 2; ++it) {
            int idx = tid + it * 512;
            int r = idx >> 4, c = (idx & 15) * 8;
            if (node0 + r < NN)
                *reinterpret_cast<uint4*>(outp + (size_t)(node0 + r) * FD + c) =
                    *reinterpret_cast<const uint4*>(&t_lds[r][c]);
        }
    }
}

extern "C" void kernel_launch(void* const* d_in, const int* in_sizes, int n_in,
                              void* d_out, int out_size, void* d_ws, size_t ws_size,
                              hipStream_t stream) {
    const float* x   = (const float*)d_in[0];
    const int*   ei  = (const int*)d_in[1];
    const float* W1a = (const float*)d_in[2];
    const float* b1a = (const float*)d_in[3];
    const float* W1b = (const float*)d_in[4];
    const float* b1b = (const float*)d_in[5];
    const float* W2a = (const float*)d_in[6];
    const float* b2a = (const float*)d_in[7];
    const float* W2b = (const float*)d_in[8];
    const float* b2b = (const float*)d_in[9];

    const size_t feat = (size_t)NN * FD;
    u16* xb = (u16*)d_ws;             // 12.8 MB (x bf16)
    u16* zb = xb + feat;              // 12.8 MB (h1 bf16)
    u16* wt = zb + feat;              // 128 KB
    int* gcnt = (int*)(wt + 4 * FD * FD);       // 1024 ints
    u32* ebuf = (u32*)(gcnt + 1024);            // NB*BCAP*4 = 4.80 MB
    u16* sbuf = (u16*)(ebuf + (size_t)NB * BCAP); // NB*BCAP*2 = 2.40 MB
    int* noff = (int*)(sbuf + (size_t)NB * BCAP); // NB*65*4 = 204 KB

    const int cBlocks = (int)(feat / (256 * 8));// 3125

    convert_x_kernel<<<cBlocks, 256, 0, stream>>>(x, xb);
    convert_w_kernel<<<4, 256, 0, stream>>>(W1a, W1b, W2a, W2b, wt);

    hipMemsetAsync(gcnt, 0, NB * sizeof(int), stream);
    bin_kernel<<<NWG_BIN, 256, 0, stream>>>(ei, ebuf, gcnt);
    sort_kernel<<<NB, 256, 0, stream>>>(ebuf, gcnt, sbuf, noff);

    // conv1: xb -> zb (bf16)
    conv_kernel<false><<<NB, 512, 0, stream>>>(
        xb, sbuf, noff, wt, b1a, wt + 1 * FD * FD, b1b, zb);
    // conv2: zb -> d_out (fp32)
    conv_kernel<true><<<NB, 512, 0, stream>>>(
        zb, sbuf, noff, wt + 2 * FD * FD, b2a, wt + 3 * FD * FD, b2b, (float*)d_out);
}